// Round 5
// baseline (173.112 us; speedup 1.0000x reference)
//
#include <hip/hip_runtime.h>
#include <hip/hip_fp16.h>

typedef _Float16 f16;
typedef _Float16 f16x8 __attribute__((ext_vector_type(8)));
typedef _Float16 f16x4 __attribute__((ext_vector_type(4)));
typedef float f32x16 __attribute__((ext_vector_type(16)));

#define NSZ 256
#define NIMG 384

// stride-256 swizzled LDS index (halves)
__device__ __forceinline__ int sw(int r, int c) { return r * NSZ + (c ^ ((r & 15) << 3)); }
// stride-32 swizzled LDS index for the small St buffer
__device__ __forceinline__ int sw32(int r, int c) { return r * 32 + (c ^ ((r & 3) << 3)); }

// Fragment-layout offset: element (row r, col c) ->
// [tile=r>>5][chunk=c>>4][lane=((c>>3)&1)*32+(r&31)][j=c&7]
__device__ __forceinline__ int frag_off(int r, int c) {
  return (((((r >> 5) * 16 + (c >> 4)) << 6) + (((c >> 3) & 1) << 5) + (r & 31)) << 3) + (c & 7);
}

// Tables: Cf = frag(C[k][h]), CTf = frag(C^T[h][k]); g[b][i] = exp(-f_i^2 tau_b).
__global__ void prep_kernel(f16* __restrict__ Cf, f16* __restrict__ CTf,
                            float* __restrict__ g, const float* __restrict__ t) {
  int k = blockIdx.x;
  int h = threadIdx.x;
  double scale = (k == 0) ? 0.0625 : 0.08838834764831844;  // sqrt(1/256), sqrt(2/256)
  double val = cos(3.14159265358979323846 * ((double)h + 0.5) * (double)k / 256.0) * scale;
  f16 vh = (f16)((float)val);
  Cf[frag_off(k, h)] = vh;   // row k, col h
  CTf[frag_off(h, k)] = vh;  // row h, col k
  if (k < 128) {
    float tb = t[k];
    float sg = expf(-0.69314718055994531f * (1.0f - tb) + 2.99573227355399099f * tb);
    float tau = 0.5f * sg * sg;
    float f = 3.14159265358979f * (float)h / 256.0f;
    g[k * NSZ + h] = expf(-f * f * tau);
  }
}

#define TBL_FRAG(Tf, tile, q, lane) (*(const f16x8*)&(Tf)[((((tile) * 16 + (q)) << 6) + (lane)) << 3])

// kernelA: per (img, n-half): E'[k 256][n-band 128] = scale .* (C X C^T), stored in
// A-fragment layout. S1+S2 fused per 32-row h-chunk of X.
__global__ __launch_bounds__(256, 2) void kernelA(
    const float* __restrict__ x, f16* __restrict__ Ep,
    const f16* __restrict__ Cf, const float* __restrict__ g) {
  __shared__ f16 Xs[32 * NSZ];   // 16 KB: current X h-chunk (f16, swizzled)
  __shared__ f16 St[128 * 32];   // 8 KB: D1^T chunk [n_local 128][h_local 32]

  int bid = blockIdx.x;
  int wg = (bid & 7) * 96 + (bid >> 3);  // XCD-chunked, bijective (768 = 8*96)
  int img = wg >> 1, half = wg & 1;
  int b = img / 3;
  const float* X = x + (size_t)img * 65536;
  f16* Ef = Ep + (size_t)img * 65536;

  int t = threadIdx.x, lane = t & 63, wave = t >> 6;
  int l31 = lane & 31, hi = lane >> 5;
  int kh = hi * 8, hi4 = hi * 4;

  const f32x16 zz = {0.f, 0.f, 0.f, 0.f, 0.f, 0.f, 0.f, 0.f,
                     0.f, 0.f, 0.f, 0.f, 0.f, 0.f, 0.f, 0.f};
  f32x16 acc2[8];
#pragma unroll
  for (int kt = 0; kt < 8; ++kt) acc2[kt] = zz;

  // preload h-chunk 0 into regs
  float4 xr0[8], xr1[8];
#pragma unroll
  for (int c = 0; c < 4; ++c) {
    int gid = t + (c << 8);
    int r = gid >> 5, gc = (gid & 31) << 3;
    xr0[c * 2] = *(const float4*)&X[r * NSZ + gc];
    xr0[c * 2 + 1] = *(const float4*)&X[r * NSZ + gc + 4];
  }

  for (int hc = 0; hc < 8; ++hc) {
    // write staged regs -> Xs
#pragma unroll
    for (int c = 0; c < 4; ++c) {
      int gid = t + (c << 8);
      int r = gid >> 5, gc = (gid & 31) << 3;
      float4 a0 = xr0[c * 2], a1 = xr0[c * 2 + 1];
      f16x8 v;
      v[0] = (f16)a0.x; v[1] = (f16)a0.y; v[2] = (f16)a0.z; v[3] = (f16)a0.w;
      v[4] = (f16)a1.x; v[5] = (f16)a1.y; v[6] = (f16)a1.z; v[7] = (f16)a1.w;
      *(f16x8*)&Xs[sw(r, gc)] = v;
    }
    // prefetch next chunk (hidden under D1+S2)
    if (hc < 7) {
#pragma unroll
      for (int c = 0; c < 4; ++c) {
        int gid = t + (c << 8);
        int r = gid >> 5, gc = (gid & 31) << 3;
        xr1[c * 2] = *(const float4*)&X[((hc + 1) * 32 + r) * NSZ + gc];
        xr1[c * 2 + 1] = *(const float4*)&X[((hc + 1) * 32 + r) * NSZ + gc + 4];
      }
    }
    __syncthreads();
    // D1[h 32][n-tile 32] = sum_w Xs[h,w] * C[n,w]; wave owns n-tile (4*half+wave)
    f32x16 acc1 = zz;
#pragma unroll
    for (int q = 0; q < 16; ++q) {
      f16x8 a = *(const f16x8*)&Xs[sw(l31, q * 16 + kh)];
      f16x8 bf = TBL_FRAG(Cf, 4 * half + wave, q, lane);
      acc1 = __builtin_amdgcn_mfma_f32_32x32x16_f16(a, bf, acc1, 0, 0, 0);
    }
    // writeT: St[n_local][h_local] (D1 col = lane, rows via v-pattern)
#pragma unroll
    for (int v2 = 0; v2 < 4; ++v2) {
      f16x4 hv;
      hv[0] = (f16)acc1[v2 * 4 + 0]; hv[1] = (f16)acc1[v2 * 4 + 1];
      hv[2] = (f16)acc1[v2 * 4 + 2]; hv[3] = (f16)acc1[v2 * 4 + 3];
      *(f16x4*)&St[sw32(32 * wave + l31, v2 * 8 + hi4)] = hv;
    }
    __syncthreads();
    // S2 partial: D2[n-tile rows][k 256] += sum_{h in chunk} St[n,h] * C[k,h]
#pragma unroll
    for (int q = 0; q < 2; ++q) {
      f16x8 a = *(const f16x8*)&St[sw32(32 * wave + l31, q * 16 + kh)];
#pragma unroll
      for (int kt = 0; kt < 8; ++kt) {
        f16x8 bf = TBL_FRAG(Cf, kt, 2 * hc + q, lane);
        acc2[kt] = __builtin_amdgcn_mfma_f32_32x32x16_f16(a, bf, acc2[kt], 0, 0, 0);
      }
    }
    if (hc < 7) {
#pragma unroll
      for (int s = 0; s < 8; ++s) xr0[s] = xr1[s];
    }
  }

  // Epilogue: D2 rows n (v-pattern), cols k (lane). scale exact, store E' in A-frag layout.
  const float* gb = g + b * NSZ;
#pragma unroll
  for (int kt = 0; kt < 8; ++kt) {
    float gk = gb[kt * 32 + l31];
#pragma unroll
    for (int v2 = 0; v2 < 4; ++v2) {
      int nl = 32 * wave + v2 * 8 + hi4;
      float4 gn4 = *(const float4*)&gb[128 * half + nl];
      float gnv[4] = {gn4.x, gn4.y, gn4.z, gn4.w};
      f16x4 hv;
#pragma unroll
      for (int e = 0; e < 4; ++e) {
        float fade = gk * gnv[e];
        float s = ((fade < 0.01f) ? 0.f : fade) * 0.999f + 0.001f;
        hv[e] = (f16)(acc2[kt][v2 * 4 + e] * s);
      }
      int qg = 2 * wave + (v2 >> 1) + 8 * half;
      int L = (v2 & 1) * 32 + l31;
      *(f16x4*)&Ef[((((kt * 16 + qg) << 6) + L) << 3) + hi4] = hv;
    }
  }
}

// kernelB: per (img, w-half): G[k][w-band] = sum_n E'[k,n] C[n,w]; Y = sum_k C[k,h] G[k,w].
__global__ __launch_bounds__(256, 2) void kernelB(
    const f16* __restrict__ Ep, float* __restrict__ out, const f16* __restrict__ CTf) {
  __shared__ f16 G[128 * NSZ];  // 64 KB: [w_local 128][k 256] swizzled

  int bid = blockIdx.x;
  int wg = (bid & 7) * 96 + (bid >> 3);
  int img = wg >> 1, half = wg & 1;
  const f16* Ef = Ep + (size_t)img * 65536;
  float* Y = out + (size_t)img * 65536 + 128 * half;

  int t = threadIdx.x, lane = t & 63, wave = t >> 6;
  int l31 = lane & 31, hi = lane >> 5, kh = hi * 8, hi4 = hi * 4;

  const f32x16 zz = {0.f, 0.f, 0.f, 0.f, 0.f, 0.f, 0.f, 0.f,
                     0.f, 0.f, 0.f, 0.f, 0.f, 0.f, 0.f, 0.f};
  f32x16 acc[2][4];
#pragma unroll
  for (int fi = 0; fi < 2; ++fi)
#pragma unroll
    for (int fj = 0; fj < 4; ++fj) acc[fi][fj] = zz;

  // S3: D3[k rows (2 tiles/wave)][w-band 128] = sum_n E'[k,n] * C[n,w]
#pragma unroll 4
  for (int q = 0; q < 16; ++q) {
    f16x8 a[2], bf[4];
    a[0] = TBL_FRAG(Ef, wave * 2 + 0, q, lane);
    a[1] = TBL_FRAG(Ef, wave * 2 + 1, q, lane);
#pragma unroll
    for (int fj = 0; fj < 4; ++fj) bf[fj] = TBL_FRAG(CTf, 4 * half + fj, q, lane);
#pragma unroll
    for (int fi = 0; fi < 2; ++fi)
#pragma unroll
      for (int fj = 0; fj < 4; ++fj)
        acc[fi][fj] = __builtin_amdgcn_mfma_f32_32x32x16_f16(a[fi], bf[fj], acc[fi][fj], 0, 0, 0);
  }
  // writeT -> G[w_local][k]
#pragma unroll
  for (int fi = 0; fi < 2; ++fi)
#pragma unroll
    for (int fj = 0; fj < 4; ++fj) {
      int crow = fj * 32 + l31;
#pragma unroll
      for (int v2 = 0; v2 < 4; ++v2) {
        int colbase = (wave * 2 + fi) * 32 + v2 * 8 + hi4;
        f16x4 hv;
        hv[0] = (f16)acc[fi][fj][v2 * 4 + 0]; hv[1] = (f16)acc[fi][fj][v2 * 4 + 1];
        hv[2] = (f16)acc[fi][fj][v2 * 4 + 2]; hv[3] = (f16)acc[fi][fj][v2 * 4 + 3];
        *(f16x4*)&G[sw(crow, colbase)] = hv;
      }
    }
  __syncthreads();

  // S4: Y[h rows (2 tiles/wave)][w-band] = sum_k C[k,h] * G[w,k]
#pragma unroll
  for (int fi = 0; fi < 2; ++fi)
#pragma unroll
    for (int fj = 0; fj < 4; ++fj) acc[fi][fj] = zz;
#pragma unroll 4
  for (int q = 0; q < 16; ++q) {
    f16x8 a[2], bf[4];
    a[0] = TBL_FRAG(CTf, wave * 2 + 0, q, lane);
    a[1] = TBL_FRAG(CTf, wave * 2 + 1, q, lane);
#pragma unroll
    for (int fj = 0; fj < 4; ++fj)
      bf[fj] = *(const f16x8*)&G[sw(fj * 32 + l31, q * 16 + kh)];
#pragma unroll
    for (int fi = 0; fi < 2; ++fi)
#pragma unroll
      for (int fj = 0; fj < 4; ++fj)
        acc[fi][fj] = __builtin_amdgcn_mfma_f32_32x32x16_f16(a[fi], bf[fj], acc[fi][fj], 0, 0, 0);
  }
  // store Y (rows h, cols w) fp32 coalesced
#pragma unroll
  for (int fi = 0; fi < 2; ++fi)
#pragma unroll
    for (int fj = 0; fj < 4; ++fj) {
      int w = fj * 32 + l31;
#pragma unroll
      for (int v2 = 0; v2 < 4; ++v2)
#pragma unroll
        for (int e = 0; e < 4; ++e) {
          int h = (wave * 2 + fi) * 32 + v2 * 8 + hi4 + e;
          Y[h * NSZ + w] = acc[fi][fj][v2 * 4 + e];
        }
    }
}

extern "C" void kernel_launch(void* const* d_in, const int* in_sizes, int n_in,
                              void* d_out, int out_size, void* d_ws, size_t ws_size,
                              hipStream_t stream) {
  const float* x = (const float*)d_in[0];
  const float* t = (const float*)d_in[1];
  float* out = (float*)d_out;

  char* ws = (char*)d_ws;
  float* g = (float*)ws;           // 131072 B
  f16* Cf = (f16*)(ws + 131072);   // 131072 B (frag layout)
  f16* CTf = (f16*)(ws + 262144);  // 131072 B (frag layout)
  f16* Ep = (f16*)(ws + 393216);   // 384*65536*2 = 50331648 B (A-frag layout)

  prep_kernel<<<256, 256, 0, stream>>>(Cf, CTf, g, t);
  kernelA<<<NIMG * 2, 256, 0, stream>>>(x, Ep, Cf, g);
  kernelB<<<NIMG * 2, 256, 0, stream>>>(Ep, out, CTf);
}

// Round 6
// 117.372 us; speedup vs baseline: 1.4749x; 1.4749x over previous
//
#include <hip/hip_runtime.h>
#include <hip/hip_fp16.h>

typedef _Float16 f16;
typedef _Float16 f16x8 __attribute__((ext_vector_type(8)));
typedef _Float16 f16x4 __attribute__((ext_vector_type(4)));
typedef float f32x16 __attribute__((ext_vector_type(16)));

#define NSZ 256
#define NIMG 384

// Swizzled LDS index (halves): row r, half-col c; XOR 16B granule by r&15.
__device__ __forceinline__ int sw(int r, int c) { return r * NSZ + (c ^ ((r & 15) << 3)); }

// Fragment-layout offset: element (row r, col c) ->
// [tile=r>>5][chunk=c>>4][lane=((c>>3)&1)*32+(r&31)][j=c&7]
__device__ __forceinline__ int frag_off(int r, int c) {
  return (((((r >> 5) * 16 + (c >> 4)) << 6) + (((c >> 3) & 1) << 5) + (r & 31)) << 3) + (c & 7);
}

// Tables: Cf = frag(C[k][h]), CTf = frag(C^T[h][k]); g[b][i]; Kq[b] = roundup32(#rows with g>=0.0099).
// g monotone-decreasing => for n>=Kq: fade = g_k*g_n <= g_n < 0.0099 < 0.01 for ALL k -> masked.
__global__ void prep_kernel(f16* __restrict__ Cf, f16* __restrict__ CTf,
                            float* __restrict__ g, int* __restrict__ Kq,
                            const float* __restrict__ t) {
  int k = blockIdx.x;
  int h = threadIdx.x;
  double scale = (k == 0) ? 0.0625 : 0.08838834764831844;  // sqrt(1/256), sqrt(2/256)
  double val = cos(3.14159265358979323846 * ((double)h + 0.5) * (double)k / 256.0) * scale;
  f16 vh = (f16)((float)val);
  Cf[frag_off(k, h)] = vh;   // row k, col h
  CTf[frag_off(h, k)] = vh;  // row h, col k
  int pred = 0;
  if (k < 128) {
    float tb = t[k];
    float sg = expf(-0.69314718055994531f * (1.0f - tb) + 2.99573227355399099f * tb);
    float tau = 0.5f * sg * sg;
    float f = 3.14159265358979f * (float)h / 256.0f;
    float gv = expf(-f * f * tau);
    g[k * NSZ + h] = gv;
    pred = (gv >= 0.0099f) ? 1 : 0;  // conservative row-keep; in-tile mask stays exact
  }
  int cnt = __syncthreads_count(pred);
  if (k < 128 && h == 0) {
    int K = ((cnt + 31) >> 5) << 5;
    if (K < 32) K = 32;
    if (K > 256) K = 256;
    Kq[k] = K;
  }
}

#define TBL_FRAG(Tf, tile, q, lane) (*(const f16x8*)&(Tf)[((((tile) * 16 + (q)) << 6) + (lane)) << 3])

// Transposed writeback to LDS with tile masks: L[c][r] = D[r][c] for
// D row-tiles rbase+fi*32 < rowLim and col-tiles cbase+fj*32 < colLim.
__device__ __forceinline__ void writeT(f16* L, int rbase, int cbase, int lane,
                                       const f32x16 (&acc)[4][2], int rowLim, int colLim) {
  int l31 = lane & 31, hi4 = (lane >> 5) * 4;
#pragma unroll
  for (int fi = 0; fi < 4; ++fi) {
    if (rbase + fi * 32 >= rowLim) continue;  // wave-uniform branch
#pragma unroll
    for (int fj = 0; fj < 2; ++fj) {
      if (cbase + fj * 32 >= colLim) continue;
      int crow = cbase + fj * 32 + l31;
#pragma unroll
      for (int v2 = 0; v2 < 4; ++v2) {
        int colbase = rbase + fi * 32 + v2 * 8 + hi4;
        f16x4 hv;
        hv[0] = (f16)acc[fi][fj][v2 * 4 + 0];
        hv[1] = (f16)acc[fi][fj][v2 * 4 + 1];
        hv[2] = (f16)acc[fi][fj][v2 * 4 + 2];
        hv[3] = (f16)acc[fi][fj][v2 * 4 + 3];
        *(f16x4*)&L[sw(crow, colbase)] = hv;
      }
    }
  }
}

__global__ __launch_bounds__(512, 2) void fused_kernel(
    const float* __restrict__ x, float* __restrict__ out,
    const f16* __restrict__ Cf, const f16* __restrict__ CTf,
    const float* __restrict__ g, const int* __restrict__ KqA) {
  __shared__ f16 L[NSZ * NSZ];  // 128 KiB

  const int img = blockIdx.x;
  const int b = img / 3;
  const int Kq = KqA[b];
  const int nq = Kq >> 4;  // 16-col k/n chunks for S3/S4 reductions
  const float* X = x + (size_t)img * 65536;
  float* Y = out + (size_t)img * 65536;

  const int t = threadIdx.x;
  const int lane = t & 63;
  const int wave = t >> 6;
  const int r0 = (wave >> 2) * 128;
  const int c0 = (wave & 3) * 64;
  const int l31 = lane & 31;
  const int kh = (lane >> 5) * 8;
  const int hi4 = (lane >> 5) * 4;
  const int tB0 = c0 >> 5;
  const int tA0 = r0 >> 5;
  const bool actB0 = tB0 * 32 < Kq;        // wave's col-tile 0 within truncated band
  const bool actB1 = (tB0 + 1) * 32 < Kq;  // wave's col-tile 1

  const f32x16 zz = {0.f, 0.f, 0.f, 0.f, 0.f, 0.f, 0.f, 0.f,
                     0.f, 0.f, 0.f, 0.f, 0.f, 0.f, 0.f, 0.f};
  f32x16 acc[4][2];
#pragma unroll
  for (int fi = 0; fi < 4; ++fi) { acc[fi][0] = zz; acc[fi][1] = zz; }

  // ---- S1: D1[h][n<Kq] = sum_w X[h,w] C[n,w]; X streamed in 4 disjoint 64-col chunks.
  // Pattern per chunk: ds_write -> barrier -> ISSUE next loads (overlap) -> compute.
  const int xr_row = t >> 1;
  const int xr_half = (t & 1) * 32;
  float4 xa[8];
#pragma unroll
  for (int s = 0; s < 8; ++s) xa[s] = *(const float4*)&X[xr_row * NSZ + xr_half + s * 4];

  for (int cw = 0; cw < 4; ++cw) {
#pragma unroll
    for (int g8 = 0; g8 < 4; ++g8) {
      float4 a0 = xa[g8 * 2], a1 = xa[g8 * 2 + 1];
      f16x8 v;
      v[0] = (f16)a0.x; v[1] = (f16)a0.y; v[2] = (f16)a0.z; v[3] = (f16)a0.w;
      v[4] = (f16)a1.x; v[5] = (f16)a1.y; v[6] = (f16)a1.z; v[7] = (f16)a1.w;
      *(f16x8*)&L[sw(xr_row, cw * 64 + xr_half + g8 * 8)] = v;
    }
    __syncthreads();
    if (cw < 3) {  // issued AFTER barrier -> genuinely overlaps the MFMA below
#pragma unroll
      for (int s = 0; s < 8; ++s)
        xa[s] = *(const float4*)&X[xr_row * NSZ + (cw + 1) * 64 + xr_half + s * 4];
    }
#pragma unroll
    for (int q4 = 0; q4 < 4; ++q4) {
      int q = cw * 4 + q4;
      f16x8 a[4];
#pragma unroll
      for (int fi = 0; fi < 4; ++fi)
        a[fi] = *(const f16x8*)&L[sw(r0 + fi * 32 + l31, q * 16 + kh)];
      if (actB0) {
        f16x8 bf = TBL_FRAG(Cf, tB0, q, lane);
#pragma unroll
        for (int fi = 0; fi < 4; ++fi)
          acc[fi][0] = __builtin_amdgcn_mfma_f32_32x32x16_f16(a[fi], bf, acc[fi][0], 0, 0, 0);
      }
      if (actB1) {
        f16x8 bf = TBL_FRAG(Cf, tB0 + 1, q, lane);
#pragma unroll
        for (int fi = 0; fi < 4; ++fi)
          acc[fi][1] = __builtin_amdgcn_mfma_f32_32x32x16_f16(a[fi], bf, acc[fi][1], 0, 0, 0);
      }
    }
    // next iteration's ds_write targets chunk cw+1 columns: disjoint from readers of cw
  }
  __syncthreads();
  writeT(L, r0, c0, lane, acc, 256, Kq);  // L1[n<Kq][h]
  __syncthreads();

  // ---- S2: D2[n<Kq][k<Kq] = sum_h L1[n,h] C[k,h] = dct_x[k,n]; scale 0.999*mask(fade).
  if (r0 < Kq) {
#pragma unroll
    for (int fi = 0; fi < 4; ++fi) { acc[fi][0] = zz; acc[fi][1] = zz; }
#pragma unroll 4
    for (int q = 0; q < 16; ++q) {
      f16x8 a[4];
#pragma unroll
      for (int fi = 0; fi < 4; ++fi)
        if (r0 + fi * 32 < Kq)
          a[fi] = *(const f16x8*)&L[sw(r0 + fi * 32 + l31, q * 16 + kh)];
      if (actB0) {
        f16x8 bf = TBL_FRAG(Cf, tB0, q, lane);
#pragma unroll
        for (int fi = 0; fi < 4; ++fi)
          if (r0 + fi * 32 < Kq)
            acc[fi][0] = __builtin_amdgcn_mfma_f32_32x32x16_f16(a[fi], bf, acc[fi][0], 0, 0, 0);
      }
      if (actB1) {
        f16x8 bf = TBL_FRAG(Cf, tB0 + 1, q, lane);
#pragma unroll
        for (int fi = 0; fi < 4; ++fi)
          if (r0 + fi * 32 < Kq)
            acc[fi][1] = __builtin_amdgcn_mfma_f32_32x32x16_f16(a[fi], bf, acc[fi][1], 0, 0, 0);
      }
    }
    // peel scale: s = (fade < 0.01) ? 0 : 0.999*fade   (cols = k, rows = n)
    const float* gb = g + b * NSZ;
#pragma unroll
    for (int fj = 0; fj < 2; ++fj) {
      if ((tB0 + fj) * 32 >= Kq) continue;
      float gk = gb[c0 + fj * 32 + l31];
#pragma unroll
      for (int fi = 0; fi < 4; ++fi) {
        if (r0 + fi * 32 >= Kq) continue;
#pragma unroll
        for (int v2 = 0; v2 < 4; ++v2) {
          float4 gn4 = *(const float4*)&gb[r0 + fi * 32 + v2 * 8 + hi4];
          float gnv[4] = {gn4.x, gn4.y, gn4.z, gn4.w};
#pragma unroll
          for (int e = 0; e < 4; ++e) {
            float fade = gk * gnv[e];
            float s = (fade < 0.01f) ? 0.f : 0.999f * fade;
            acc[fi][fj][v2 * 4 + e] *= s;
          }
        }
      }
    }
  }
  __syncthreads();
  writeT(L, r0, c0, lane, acc, Kq, Kq);  // L2[k<Kq][n<Kq]
  __syncthreads();

  // ---- S3: D3[k<Kq][w] = sum_{n<Kq} L2[k,n] C[n,w]
#pragma unroll
  for (int fi = 0; fi < 4; ++fi) { acc[fi][0] = zz; acc[fi][1] = zz; }
  if (r0 < Kq) {
    for (int q = 0; q < nq; ++q) {
      f16x8 a[4];
#pragma unroll
      for (int fi = 0; fi < 4; ++fi)
        if (r0 + fi * 32 < Kq)
          a[fi] = *(const f16x8*)&L[sw(r0 + fi * 32 + l31, q * 16 + kh)];
      f16x8 b0 = TBL_FRAG(CTf, tB0, q, lane);
      f16x8 b1 = TBL_FRAG(CTf, tB0 + 1, q, lane);
#pragma unroll
      for (int fi = 0; fi < 4; ++fi)
        if (r0 + fi * 32 < Kq) {
          acc[fi][0] = __builtin_amdgcn_mfma_f32_32x32x16_f16(a[fi], b0, acc[fi][0], 0, 0, 0);
          acc[fi][1] = __builtin_amdgcn_mfma_f32_32x32x16_f16(a[fi], b1, acc[fi][1], 0, 0, 0);
        }
    }
  }
  __syncthreads();
  writeT(L, r0, c0, lane, acc, Kq, 256);  // L3[w][k<Kq]
  __syncthreads();

  // ---- S4: Y[h][w] = 0.001*X + sum_{k<Kq} C[k,h] L3[w,k]; per-fj slab so stores
  // of slab 0 drain under slab 1's MFMA.
#pragma unroll
  for (int fj = 0; fj < 2; ++fj) {
#pragma unroll
    for (int fi = 0; fi < 4; ++fi) acc[fi][fj] = zz;
    for (int q = 0; q < nq; ++q) {
      f16x8 bf = *(const f16x8*)&L[sw(c0 + fj * 32 + l31, q * 16 + kh)];
#pragma unroll
      for (int fi = 0; fi < 4; ++fi) {
        f16x8 a = TBL_FRAG(CTf, tA0 + fi, q, lane);
        acc[fi][fj] = __builtin_amdgcn_mfma_f32_32x32x16_f16(a, bf, acc[fi][fj], 0, 0, 0);
      }
    }
    int w = c0 + fj * 32 + l31;
#pragma unroll
    for (int fi = 0; fi < 4; ++fi)
#pragma unroll
      for (int v2 = 0; v2 < 4; ++v2)
#pragma unroll
        for (int e = 0; e < 4; ++e) {
          int h = r0 + fi * 32 + v2 * 8 + hi4 + e;
          Y[h * NSZ + w] = acc[fi][fj][v2 * 4 + e] + 0.001f * X[h * NSZ + w];
        }
  }
}

extern "C" void kernel_launch(void* const* d_in, const int* in_sizes, int n_in,
                              void* d_out, int out_size, void* d_ws, size_t ws_size,
                              hipStream_t stream) {
  const float* x = (const float*)d_in[0];
  const float* t = (const float*)d_in[1];
  float* out = (float*)d_out;

  char* ws = (char*)d_ws;
  float* g = (float*)ws;           // 131072 B
  f16* Cf = (f16*)(ws + 131072);   // 131072 B (frag layout)
  f16* CTf = (f16*)(ws + 262144);  // 131072 B (frag layout)
  int* Kq = (int*)(ws + 393216);   // 512 B

  prep_kernel<<<256, 256, 0, stream>>>(Cf, CTf, g, Kq, t);
  fused_kernel<<<NIMG, 512, 0, stream>>>(x, out, Cf, CTf, g, Kq);
}